// Round 13
// baseline (263.136 us; speedup 1.0000x reference)
//
#include <hip/hip_runtime.h>
#include <hip/hip_fp16.h>
#include <math.h>

#define NS 0.2f  // leaky_relu negative slope

__device__ __forceinline__ float lrelu(float x) { return fmaxf(x, NS * x); }

// ---------------- dense feature kernels ----------------
// H is stored fp16 (one N x 32 table); scores + AGG stay f32.

__global__ __launch_bounds__(256) void k_feat1(
    const float* __restrict__ X, const float* __restrict__ W,
    const float* __restrict__ a_s, const float* __restrict__ a_d,
    __half* __restrict__ H, float* __restrict__ Ss, float* __restrict__ Sd, int n)
{
    __shared__ float Wl[128 * 32];
    __shared__ float Xl[8 * 128];
    const int tid = threadIdx.x;
    for (int i = tid; i < 128 * 32; i += 256) Wl[i] = W[i];

    const int row0 = blockIdx.x * 8;
    {
        int idx = tid * 4;
        int r = idx >> 7, c = idx & 127;
        if (row0 + r < n)
            *reinterpret_cast<float4*>(&Xl[idx]) =
                *reinterpret_cast<const float4*>(&X[(size_t)(row0 + r) * 128 + c]);
    }
    __syncthreads();

    const int r = tid >> 5, c = tid & 31;
    const int row = row0 + r;
    if (row >= n) return;

    float acc = 0.f;
#pragma unroll
    for (int k = 0; k < 128; ++k) acc += Xl[r * 128 + k] * Wl[k * 32 + c];
    H[(size_t)row * 32 + c] = __float2half(acc);

    float vs = acc * a_s[c];
    float vd = acc * a_d[c];
#pragma unroll
    for (int o = 16; o; o >>= 1) { vs += __shfl_xor(vs, o, 32); vd += __shfl_xor(vd, o, 32); }
    if (c == 0) { Ss[row] = vs; Sd[row] = vd; }
}

__global__ __launch_bounds__(256) void k_feat2(
    const float* __restrict__ In, const float* __restrict__ W,
    const float* __restrict__ bias,
    const float* __restrict__ a_s, const float* __restrict__ a_d,
    __half* __restrict__ H, float* __restrict__ Ss, float* __restrict__ Sd, int n)
{
    __shared__ float Wl[32 * 32];
    __shared__ float Xl[8 * 32];
    const int tid = threadIdx.x;
    for (int i = tid; i < 1024; i += 256) Wl[i] = W[i];

    const int r = tid >> 5, c = tid & 31;
    const int row = blockIdx.x * 8 + r;
    if (row < n) Xl[tid] = fmaxf(In[(size_t)row * 32 + c] + bias[c], 0.f);
    __syncthreads();
    if (row >= n) return;

    float acc = 0.f;
#pragma unroll
    for (int k = 0; k < 32; ++k) acc += Xl[r * 32 + k] * Wl[k * 32 + c];
    H[(size_t)row * 32 + c] = __float2half(acc);

    float vs = acc * a_s[c];
    float vd = acc * a_d[c];
#pragma unroll
    for (int o = 16; o; o >>= 1) { vs += __shfl_xor(vs, o, 32); vd += __shfl_xor(vd, o, 32); }
    if (c == 0) { Ss[row] = vs; Sd[row] = vd; }
}

__global__ __launch_bounds__(256) void k_cls(
    const float* __restrict__ In, const float* __restrict__ W,
    const float* __restrict__ b_prev, const float* __restrict__ bc,
    float* __restrict__ Out, int n)
{
    __shared__ float Wl[32 * 32];
    __shared__ float Xl[8 * 32];
    const int tid = threadIdx.x;
    for (int i = tid; i < 1024; i += 256) Wl[i] = W[i];

    const int r = tid >> 5, c = tid & 31;
    const int row = blockIdx.x * 8 + r;
    if (row < n) Xl[tid] = fmaxf(In[(size_t)row * 32 + c] + b_prev[c], 0.f);
    __syncthreads();
    if (row >= n) return;

    float acc = bc[c];
#pragma unroll
    for (int k = 0; k < 32; ++k) acc += Xl[r * 32 + k] * Wl[k * 32 + c];
    Out[(size_t)row * 32 + c] = 1.f / (1.f + __expf(-acc));
}

// ---------------- bucketed CSR build ----------------
// Buckets of 256 consecutive dst nodes. ngroups = ceil(N/256) (must be <= 511).

#define NBH 256   // histogram blocks (persistent, 1 per CU)
#define BPAD 32   // bcur padding: one counter per 128B line

// coarse bucket histogram: LDS-private per block, store partials (NO global atomics)
__global__ __launch_bounds__(256) void k_bhist(const int* __restrict__ edst, int E,
                                               int* __restrict__ hpart, int ngroups)
{
    __shared__ int h[512];
    const int tid = threadIdx.x;
    for (int i = tid; i < ngroups; i += 256) h[i] = 0;
    __syncthreads();
    const int nv = E >> 2;
    for (int i = blockIdx.x * 256 + tid; i < nv; i += NBH * 256) {
        int4 d = *reinterpret_cast<const int4*>(&edst[i << 2]);
        atomicAdd(&h[d.x >> 8], 1); atomicAdd(&h[d.y >> 8], 1);
        atomicAdd(&h[d.z >> 8], 1); atomicAdd(&h[d.w >> 8], 1);
    }
    if (blockIdx.x == 0 && tid < (E & 3))
        atomicAdd(&h[edst[(nv << 2) + tid] >> 8], 1);
    __syncthreads();
    for (int i = tid; i < ngroups; i += 256) hpart[i * NBH + blockIdx.x] = h[i];
}

// single block: reduce partials, exclusive scan -> bstart; init padded bcur; off[N]=E+N
__global__ __launch_bounds__(512) void k_bscan(const int* __restrict__ hpart, int ngroups,
    int* __restrict__ bstart, int* __restrict__ bcur, int* __restrict__ off,
    int N, int E)
{
    __shared__ int sm[512];
    int t = threadIdx.x;
    int v = 0;
    if (t < ngroups) {
        const int4* row = reinterpret_cast<const int4*>(&hpart[t * NBH]);
#pragma unroll 4
        for (int b = 0; b < NBH / 4; ++b) { int4 x = row[b]; v += x.x + x.y + x.z + x.w; }
    }
    sm[t] = v; __syncthreads();
    for (int o = 1; o < 512; o <<= 1) {
        int x = sm[t];
        if (t >= o) x += sm[t - o];
        __syncthreads();
        sm[t] = x;
        __syncthreads();
    }
    if (t <= ngroups) {
        int ex = (t == 0) ? 0 : sm[t - 1];
        bstart[t] = ex;
        if (t < ngroups) bcur[t * BPAD] = ex;
    }
    if (t == 0) off[N] = E + N;
}

// pass 1: partition packed records (dstlow<<24 | src) by dst>>8 into ebuf
#define CHUNK 4096
#define KPT 8

__global__ __launch_bounds__(512) void k_part(
    const int* __restrict__ esrc, const int* __restrict__ edst, int E,
    int* __restrict__ bcur, unsigned int* __restrict__ ebuf, int ngroups)
{
    __shared__ int hist[512];
    __shared__ int lofs[513];
    __shared__ int gbase[512];
    __shared__ unsigned int stage[CHUNK];
    __shared__ unsigned short bstage[CHUNK];
    const int tid = threadIdx.x;

    for (int c0 = blockIdx.x * CHUNK; c0 < E; c0 += gridDim.x * CHUNK) {
        const int cnt = min(CHUNK, E - c0);
        if (tid < 512) hist[tid] = 0;
        __syncthreads();

        int bp[KPT];   // (b<<20) | (dstlow<<12) | pos   (pos < 4096)
#pragma unroll
        for (int k = 0; k < KPT; ++k) {
            int i = c0 + k * 512 + tid;
            bp[k] = -1;
            if (i < E) {
                int d = edst[i];
                int b = d >> 8;
                int pos = atomicAdd(&hist[b], 1);
                bp[k] = (b << 20) | ((d & 255) << 12) | pos;
            }
        }
        __syncthreads();

        if (tid < 64) {           // exclusive scan of hist[0..512) by one wave
            int base = tid * 8, v[8], s = 0;
#pragma unroll
            for (int k = 0; k < 8; ++k) { v[k] = hist[base + k]; s += v[k]; }
            int pre = s;
            for (int o = 1; o < 64; o <<= 1) {
                int t2 = __shfl_up(pre, o, 64);
                if (tid >= o) pre += t2;
            }
            pre -= s;
#pragma unroll
            for (int k = 0; k < 8; ++k) { lofs[base + k] = pre; pre += v[k]; }
            if (tid == 63) lofs[512] = pre;
        }
        __syncthreads();

        for (int b = tid; b < ngroups; b += 512)
            if (hist[b] > 0) gbase[b] = atomicAdd(&bcur[b * BPAD], hist[b]);
        __syncthreads();

#pragma unroll
        for (int k = 0; k < KPT; ++k) {
            if (bp[k] >= 0) {
                int i = c0 + k * 512 + tid;
                int b = bp[k] >> 20, dl = (bp[k] >> 12) & 255, pos = bp[k] & 4095;
                int slot = lofs[b] + pos;
                stage[slot] = ((unsigned)dl << 24) | (unsigned)esrc[i];
                bstage[slot] = (unsigned short)b;
            }
        }
        __syncthreads();

        for (int i = tid; i < cnt; i += 512) {
            int b = bstage[i];
            ebuf[(size_t)gbase[b] + (i - lofs[b])] = stage[i];
        }
        __syncthreads();
    }
}

// pass 2: one block per bucket. Count per-node degree in LDS, scan (+self-loop),
// write off[] and the sorted segment fully coalesced.
#define RCAP 11264  // 44KB

__global__ __launch_bounds__(256) void k_place2(
    const unsigned int* __restrict__ ebuf, const int* __restrict__ bstart,
    int* __restrict__ off, int* __restrict__ esorted, int* __restrict__ gcur, int N)
{
    __shared__ int R[RCAP];
    __shared__ int cnt[256];
    __shared__ int lcur[256];
    __shared__ int sm[256];
    const int g = blockIdx.x, tid = threadIdx.x;
    const int d0 = g << 8, d1 = min(d0 + 256, N);
    const int nd = d1 - d0;
    const int eb = bstart[g];
    const int ecnt = bstart[g + 1] - eb;
    const int base = eb + d0;               // segment start incl. preceding self-loops
    const int len = ecnt + nd;

    cnt[tid] = 0;
    __syncthreads();
    for (int i = tid; i < ecnt; i += 256)
        atomicAdd(&cnt[ebuf[eb + i] >> 24], 1);
    __syncthreads();

    int v = (tid < nd) ? cnt[tid] + 1 : 0;
    sm[tid] = v; __syncthreads();
    for (int o = 1; o < 256; o <<= 1) {
        int x = sm[tid];
        if (tid >= o) x += sm[tid - o];
        __syncthreads();
        sm[tid] = x;
        __syncthreads();
    }
    int lo = sm[tid] - v;                    // exclusive

    if (len <= RCAP) {
        if (tid < nd) {
            off[d0 + tid] = base + lo;
            R[lo] = d0 + tid;                // self-loop at segment head
            lcur[tid] = lo + 1;
        }
        __syncthreads();
        for (int i = tid; i < ecnt; i += 256) {
            unsigned int w = ebuf[eb + i];
            int pos = atomicAdd(&lcur[w >> 24], 1);
            R[pos] = (int)(w & 0xffffffu);
        }
        __syncthreads();
        for (int i = tid; i < len; i += 256) esorted[base + i] = R[i];
    } else {                                 // overflow fallback (statistically never)
        if (tid < nd) {
            off[d0 + tid] = base + lo;
            esorted[base + lo] = d0 + tid;
            gcur[d0 + tid] = base + lo + 1;
        }
        __syncthreads();
        for (int i = tid; i < ecnt; i += 256) {
            unsigned int w = ebuf[eb + i];
            esorted[atomicAdd(&gcur[d0 + (int)(w >> 24)], 1)] = (int)(w & 0xffffffu);
        }
    }
}

// ---------------- fused GAT aggregation ----------------
// TWO nodes per 64-lane wave, chains fully interleaved: both esorted loads,
// both Ss gathers, both exps, then ALL 8 H-gathers (4/node, exec-masked) are
// issued before any consume -> up to 8 loads in flight per wave (the kernel is
// per-wave chain-latency bound). deg>64 handled by a generic tail loop.
// No max-shift: ratio is shift-invariant; |scores| <= ~12 so exp can't overflow.

__global__ __launch_bounds__(256) void k_gat(
    const int* __restrict__ off, const int* __restrict__ esorted,
    const float* __restrict__ Ss, const float* __restrict__ Sd,
    const uint4* __restrict__ H4, float* __restrict__ out, int n)
{
    const int gA = (blockIdx.x * 4 + (threadIdx.x >> 6)) * 2;
    if (gA >= n) return;
    const int gB = gA + 1;
    const bool hasB = (gB < n);
    const int lane = threadIdx.x & 63;
    const int hf = lane & 3, q = lane >> 2;   // q in [0,16)

    const int j0A = off[gA], j1A = off[gA + 1];
    const int j0B = hasB ? j1A : 0, j1B = hasB ? off[gB + 1] : 0;  // off[gB]==j1A
    const float sdA = Sd[gA];
    const float sdB = hasB ? Sd[gB] : 0.f;

    // ---- setup: interleaved loads for both nodes ----
    int eA = j0A + lane, eB = j0B + lane;
    int rA = (eA < j1A) ? esorted[eA] : -1;
    int rB = (eB < j1B) ? esorted[eB] : -1;
    float ssA = (rA >= 0) ? Ss[rA] : 0.f;
    float ssB = (rB >= 0) ? Ss[rB] : 0.f;
    int   sA = (rA >= 0) ? rA : 0;
    int   sB = (rB >= 0) ? rB : 0;
    float wA = 0.f, wB = 0.f;
    if (rA >= 0) { float t = ssA + sdA; wA = __expf(fmaxf(t, NS * t)); }
    if (rB >= 0) { float t = ssB + sdB; wB = __expf(fmaxf(t, NS * t)); }
    float zA = wA, zB = wB;

    const int mA = min(64, j1A - j0A);
    const int mB = min(64, j1B - j0B);  // 0 if !hasB

    float accA[8] = {0.f,0.f,0.f,0.f,0.f,0.f,0.f,0.f};
    float accB[8] = {0.f,0.f,0.f,0.f,0.f,0.f,0.f,0.f};

    // ---- gather phase: issue all 8 loads (exec-masked), then consume ----
    {
        int   sAk[4], sBk[4];
        float wAk[4], wBk[4];
        uint4 hA[4], hB[4];
#pragma unroll
        for (int i = 0; i < 4; ++i) {
            sAk[i] = __shfl(sA, i * 16 + q);
            wAk[i] = __shfl(wA, i * 16 + q);
            hA[i] = make_uint4(0u, 0u, 0u, 0u);
            if (i * 16 + q < mA) hA[i] = H4[(size_t)sAk[i] * 4 + hf];
        }
#pragma unroll
        for (int i = 0; i < 4; ++i) {
            sBk[i] = __shfl(sB, i * 16 + q);
            wBk[i] = __shfl(wB, i * 16 + q);
            hB[i] = make_uint4(0u, 0u, 0u, 0u);
            if (i * 16 + q < mB) hB[i] = H4[(size_t)sBk[i] * 4 + hf];
        }
#pragma unroll
        for (int i = 0; i < 4; ++i) {
            float w = wAk[i];
            const __half2* hp = reinterpret_cast<const __half2*>(&hA[i]);
#pragma unroll
            for (int j = 0; j < 4; ++j) {
                float2 f = __half22float2(hp[j]);
                accA[j * 2]     += w * f.x;
                accA[j * 2 + 1] += w * f.y;
            }
        }
#pragma unroll
        for (int i = 0; i < 4; ++i) {
            float w = wBk[i];
            const __half2* hp = reinterpret_cast<const __half2*>(&hB[i]);
#pragma unroll
            for (int j = 0; j < 4; ++j) {
                float2 f = __half22float2(hp[j]);
                accB[j * 2]     += w * f.x;
                accB[j * 2 + 1] += w * f.y;
            }
        }
    }

    // ---- tail blocks (deg > 64; statistically near-never) ----
    for (int b0 = j0A + 64; b0 < j1A; b0 += 64) {
        int e = b0 + lane;
        int sT = 0; float wT = 0.f;
        if (e < j1A) { sT = esorted[e]; float t = Ss[sT] + sdA; wT = __expf(fmaxf(t, NS * t)); }
        zA += wT;
        const int m = min(64, j1A - b0);
        for (int k = 0; k < m; k += 16) {
            int   src = __shfl(sT, k + q);
            float w   = __shfl(wT, k + q);
            if (k + q < m) {
                uint4 hv = H4[(size_t)src * 4 + hf];
                const __half2* hp = reinterpret_cast<const __half2*>(&hv);
#pragma unroll
                for (int j = 0; j < 4; ++j) {
                    float2 f = __half22float2(hp[j]);
                    accA[j * 2]     += w * f.x;
                    accA[j * 2 + 1] += w * f.y;
                }
            }
        }
    }
    for (int b0 = j0B + 64; b0 < j1B; b0 += 64) {
        int e = b0 + lane;
        int sT = 0; float wT = 0.f;
        if (e < j1B) { sT = esorted[e]; float t = Ss[sT] + sdB; wT = __expf(fmaxf(t, NS * t)); }
        zB += wT;
        const int m = min(64, j1B - b0);
        for (int k = 0; k < m; k += 16) {
            int   src = __shfl(sT, k + q);
            float w   = __shfl(wT, k + q);
            if (k + q < m) {
                uint4 hv = H4[(size_t)src * 4 + hf];
                const __half2* hp = reinterpret_cast<const __half2*>(&hv);
#pragma unroll
                for (int j = 0; j < 4; ++j) {
                    float2 f = __half22float2(hp[j]);
                    accB[j * 2]     += w * f.x;
                    accB[j * 2 + 1] += w * f.y;
                }
            }
        }
    }

    // ---- reductions (over q: lanes sharing hf) ----
#pragma unroll
    for (int o = 4; o <= 32; o <<= 1) {
#pragma unroll
        for (int j = 0; j < 8; ++j) {
            accA[j] += __shfl_xor(accA[j], o);
            accB[j] += __shfl_xor(accB[j], o);
        }
        zA += __shfl_xor(zA, o);
        zB += __shfl_xor(zB, o);
    }
    zA += __shfl_xor(zA, 1); zA += __shfl_xor(zA, 2);
    zB += __shfl_xor(zB, 1); zB += __shfl_xor(zB, 2);

    if (q == 0) {
        float invA = 1.f / (zA + 1e-16f);
        float4 r0 = { accA[0] * invA, accA[1] * invA, accA[2] * invA, accA[3] * invA };
        float4 r1 = { accA[4] * invA, accA[5] * invA, accA[6] * invA, accA[7] * invA };
        float* o32 = &out[(size_t)gA * 32 + hf * 8];
        *reinterpret_cast<float4*>(o32)     = r0;
        *reinterpret_cast<float4*>(o32 + 4) = r1;
        if (hasB) {
            float invB = 1.f / (zB + 1e-16f);
            float4 r2 = { accB[0] * invB, accB[1] * invB, accB[2] * invB, accB[3] * invB };
            float4 r3 = { accB[4] * invB, accB[5] * invB, accB[6] * invB, accB[7] * invB };
            float* p32 = &out[(size_t)gB * 32 + hf * 8];
            *reinterpret_cast<float4*>(p32)     = r2;
            *reinterpret_cast<float4*>(p32 + 4) = r3;
        }
    }
}

// ---------------- launch ----------------

extern "C" void kernel_launch(void* const* d_in, const int* in_sizes, int n_in,
                              void* d_out, int out_size, void* d_ws, size_t ws_size,
                              hipStream_t stream)
{
    const float* x   = (const float*)d_in[0];
    const int*   ei  = (const int*)d_in[1];
    const float* W1  = (const float*)d_in[2];
    const float* as1 = (const float*)d_in[3];
    const float* ad1 = (const float*)d_in[4];
    const float* b1  = (const float*)d_in[5];
    const float* W2  = (const float*)d_in[6];
    const float* as2 = (const float*)d_in[7];
    const float* ad2 = (const float*)d_in[8];
    const float* b2  = (const float*)d_in[9];
    const float* Wc  = (const float*)d_in[10];
    const float* bc  = (const float*)d_in[11];

    const int N = in_sizes[0] / 128;
    const int E = in_sizes[1] / 2;
    const int* esrc = ei;
    const int* edst = ei + E;
    const int ngroups = (N + 255) >> 8;      // must be <= 511

    // workspace carve-up
    char* p = (char*)d_ws;
    __half* H    = (__half*)p; p += (size_t)N * 32 * 2;  // 6.4 MB ┐ ebuf (12.8MB) aliases
    float* AGG   = (float*)p;  p += (size_t)N * 32 * 4;  // 12.8MB ┘ H+AGG (build only)
    float* Ss    = (float*)p;  p += (size_t)N * 4;
    float* Sd    = (float*)p;  p += (size_t)N * 4;
    int*   off   = (int*)p;    p += (size_t)(N + 1) * 4;
    int*   gcur  = (int*)p;    p += (size_t)N * 4;       // overflow fallback only
    int*   hpart = (int*)p;    p += 512 * NBH * 4;       // 512 KB histogram partials
    int*   bstart= (int*)p;    p += 513 * 4;
    int*   bcur  = (int*)p;    p += 512 * BPAD * 4;      // 64 KB padded cursors
    int*   esort = (int*)p;    p += (size_t)(E + N) * 4; // 13.2 MB

    unsigned int* ebuf = (unsigned int*)H;               // 12.8 MB alias (build only)
    const uint4* H4 = (const uint4*)H;                   // H rows as 4x uint4

    const dim3 blk(256);
    const int nb_rows = (N + 7) / 8;
    const int nb_part = (E + CHUNK - 1) / CHUNK;
    const int nb_gat  = (N + 7) / 8;         // 4 waves/block x 2 nodes/wave

    // ---- bucketed CSR build (by dst), shared by both layers ----
    k_bhist<<<NBH, blk, 0, stream>>>(edst, E, hpart, ngroups);
    k_bscan<<<1, 512, 0, stream>>>(hpart, ngroups, bstart, bcur, off, N, E);
    k_part<<<nb_part, 512, 0, stream>>>(esrc, edst, E, bcur, ebuf, ngroups);
    k_place2<<<ngroups, blk, 0, stream>>>(ebuf, bstart, off, esort, gcur, N);

    // ---- Layer 1 ----  (feat1 overwrites H => ebuf dead from here on)
    k_feat1<<<nb_rows, blk, 0, stream>>>(x, W1, as1, ad1, H, Ss, Sd, N);
    k_gat<<<nb_gat, blk, 0, stream>>>(off, esort, Ss, Sd, H4, AGG, N);

    // ---- Layer 2 ----
    k_feat2<<<nb_rows, blk, 0, stream>>>(AGG, W2, b1, as2, ad2, H, Ss, Sd, N);
    k_gat<<<nb_gat, blk, 0, stream>>>(off, esort, Ss, Sd, H4, AGG, N);

    // ---- Classifier ----
    k_cls<<<nb_rows, blk, 0, stream>>>(AGG, Wc, b2, bc, (float*)d_out, N);
}